// Round 1
// baseline (309.153 us; speedup 1.0000x reference)
//
#include <hip/hip_runtime.h>

// Problem constants (match reference)
#define B_   256
#define M_   16
#define A_   4096
#define NS_  1024
#define T_   64
#define AT_  (A_ + T_)

static constexpr float DTc = 0.001f;
static constexpr float DAc = 0.001f;

// Output layout (flat, concatenated in reference return order)
static constexpr size_t OFF_AT    = 0;                         // A_t   (B*M)
static constexpr size_t OFF_Z     = 4096;                      // Z     (B*M)
static constexpr size_t OFF_ZNLL  = 8192;                      // Z_nll (B*M)
static constexpr size_t OFF_LNPY  = 12288;                     // lnPy  (B*M*NS)
static constexpr size_t OFF_LNP1Y = 12288 + 4194304;           // lnP1_y
static constexpr size_t OFF_VT    = 12288 + 2ull * 4194304;    // V_t_new (B*M*A)
static constexpr size_t OFF_SNV   = OFF_VT + 16777216ull;      // snv_new
static constexpr size_t OFF_ISYN  = OFF_SNV + 4194304ull;      // I_syn (B*M)

__global__ __launch_bounds__(256) void lif_kernel(
    const float* __restrict__ x,
    const float* __restrict__ V_t_old,
    const float* __restrict__ logS_t_old,
    const float* __restrict__ snv_in,
    const float* __restrict__ snlf,
    const float* __restrict__ I_syn,
    const float* __restrict__ amem,
    const float* __restrict__ asyn,
    const float* __restrict__ J,
    const float* __restrict__ rp,
    const float* __restrict__ ft,
    const float* __restrict__ eps,
    const float* __restrict__ Z_hist,
    const int*   __restrict__ clk_ptr,
    float* __restrict__ out)
{
    const int row = blockIdx.x;      // b*M + m
    const int b   = row >> 4;
    const int m   = row & 15;
    const int tid = threadIdx.x;

    __shared__ float sh_I[M_];
    __shared__ float sh_inT;
    __shared__ float sh_red[4][4];

    const int clk = *clk_ptr;

    // ---- I_syn update (per b, all m') + input_total for this (b,m) ----
    if (tid < M_) {
        float es   = expf(-DTc * asyn[tid]);
        float Iold = I_syn[b * M_ + tid];
        float In   = Iold;
        if (clk > 1) {  // SYN_DELAY_BINS = 1
            float zl = Z_hist[(size_t)(b * M_ + tid) * AT_ + (clk + A_ - 2)];
            In = es * Iold + (1.0f - es) * zl / DTc;
        }
        sh_I[tid] = In;
    }
    __syncthreads();
    if (tid == 0) {
        float dot = 0.0f;
#pragma unroll
        for (int mm = 0; mm < M_; ++mm) dot += sh_I[mm] * J[mm * M_ + m];
        sh_inT = dot + x[row] * eps[0];
        out[OFF_ISYN + row] = sh_I[m];
    }
    __syncthreads();

    const float a_m  = amem[m];
    const float rp_m = rp[m];
    const float ft_m = ft[m];
    const float inT  = sh_inT;

    const size_t rowA = (size_t)row * A_;
    const size_t rowZ = (size_t)row * AT_;

    // ---- main A loop: 4 chunks of float4 per thread ----
    float sZm = 0.0f, sM = 0.0f, sNum = 0.0f, sDen = 0.0f;

#pragma unroll
    for (int c = 0; c < 4; ++c) {
        const int a0 = c * 1024 + tid * 4;
        const float4 vo = *reinterpret_cast<const float4*>(V_t_old    + rowA + a0);
        const float4 ls = *reinterpret_cast<const float4*>(logS_t_old + rowA + a0);
        const float vov[4] = {vo.x, vo.y, vo.z, vo.w};
        const float lsv[4] = {ls.x, ls.y, ls.z, ls.w};
        // reversed Z window: Z_t[a] = Z_hist[rowZ + clk + A - 1 - a]
        const float* zp = Z_hist + rowZ + (clk + A_ - 1 - a0);
        float vres[4];
#pragma unroll
        for (int k = 0; k < 4; ++k) {
            const int a = a0 + k;
            float V = vov[k] + DAc * (rp_m - vov[k]) * a_m + DAc * inT;
            if (a < 4) V = 0.0f;                       // age < REF_T (a*DA < 0.004)
            float lam  = (V == 0.0f) ? 1e-8f : expf(V - ft_m);
            float p    = lam * DTc;
            float Plam = (p >= 0.01f) ? (1.0f - expf(-p)) : p;
            float S    = expf(lsv[k]);
            float z    = zp[-k];
            float mt   = S * z;
            sZm += mt * Plam;
            sM  += mt;
            float v = (1.0f - S) * mt;
            sNum += v * Plam;
            sDen += v;
            vres[k] = V;
        }
        *reinterpret_cast<float4*>(out + OFF_VT + rowA + a0) =
            make_float4(vres[0], vres[1], vres[2], vres[3]);
    }

    // ---- block reduction of the 4 sums ----
    float vals[4] = {sZm, sM, sNum, sDen};
#pragma unroll
    for (int i = 0; i < 4; ++i) {
        float v = vals[i];
        for (int off = 32; off > 0; off >>= 1) v += __shfl_down(v, off, 64);
        vals[i] = v;
    }
    const int wave = tid >> 6, lane = tid & 63;
    if (lane == 0) {
#pragma unroll
        for (int i = 0; i < 4; ++i) sh_red[wave][i] = vals[i];
    }
    __syncthreads();
    if (tid == 0) {
        float Zm  = sh_red[0][0] + sh_red[1][0] + sh_red[2][0] + sh_red[3][0];
        float sMt = sh_red[0][1] + sh_red[1][1] + sh_red[2][1] + sh_red[3][1];
        float num = sh_red[0][2] + sh_red[1][2] + sh_red[2][2] + sh_red[3][2];
        float den = sh_red[0][3] + sh_red[1][3] + sh_red[2][3] + sh_red[3][3];
        float mess  = 1.0f - sMt;
        float lam_t = (den != 0.0f) ? (num / den) : 0.0f;
        float Z = Zm + lam_t * mess;
        Z = fminf(fmaxf(Z, 0.0f), 1.0f);
        float At  = Z / DTc;
        float var = Z / 500.0f + 0.1f * DTc / 500.0f;
        float ztn = Z_hist[rowZ + clk + A_];
        float d   = ztn - Z;
        float znll = 0.5f * (d * d) / var + 0.5f * logf(var) + 0.5f * logf(2.0f * 3.14f);
        out[OFF_AT   + row] = At;
        out[OFF_Z    + row] = Z;
        out[OFF_ZNLL + row] = znll;
    }

    // ---- sampled-neuron part: 1 float4 per thread ----
    {
        const size_t rowS = (size_t)row * NS_;
        const int s0 = tid * 4;
        const float4 v4  = *reinterpret_cast<const float4*>(snv_in + rowS + s0);
        const float4 lf4 = *reinterpret_cast<const float4*>(snlf   + rowS + s0);
        const float vv[4] = {v4.x, v4.y, v4.z, v4.w};
        const float lf[4] = {lf4.x, lf4.y, lf4.z, lf4.w};
        float vn[4], py[4], p1[4];
#pragma unroll
        for (int k = 0; k < 4; ++k) {
            float V = vv[k] + DAc * (rp_m - vv[k]) * a_m + DAc * inT;
            if (lf[k] < 0.004f) V = 0.0f;              // age < REF_T
            float lam  = (V == 0.0f) ? 1e-8f : expf(V - ft_m);
            float ltdt = lam * DTc;
            float Plam = (ltdt >= 0.01f) ? (1.0f - expf(-ltdt)) : ltdt;
            py[k] = (ltdt < 0.01f) ? (V - ft_m + logf(DTc)) : logf(Plam);
            p1[k] = -ltdt;
            vn[k] = V;
        }
        *reinterpret_cast<float4*>(out + OFF_SNV   + rowS + s0) = make_float4(vn[0], vn[1], vn[2], vn[3]);
        *reinterpret_cast<float4*>(out + OFF_LNPY  + rowS + s0) = make_float4(py[0], py[1], py[2], py[3]);
        *reinterpret_cast<float4*>(out + OFF_LNP1Y + rowS + s0) = make_float4(p1[0], p1[1], p1[2], p1[3]);
    }
}

extern "C" void kernel_launch(void* const* d_in, const int* in_sizes, int n_in,
                              void* d_out, int out_size, void* d_ws, size_t ws_size,
                              hipStream_t stream) {
    lif_kernel<<<B_ * M_, 256, 0, stream>>>(
        (const float*)d_in[0],   // x
        (const float*)d_in[1],   // V_t_old
        (const float*)d_in[2],   // logS_t_old
        (const float*)d_in[3],   // sampled_neuron_v
        (const float*)d_in[4],   // sampled_neuron_lastfire
        (const float*)d_in[5],   // I_syn
        (const float*)d_in[6],   // amem
        (const float*)d_in[7],   // asyn
        (const float*)d_in[8],   // J
        (const float*)d_in[9],   // rp
        (const float*)d_in[10],  // ft
        (const float*)d_in[11],  // eps
        (const float*)d_in[12],  // Z_hist_est
        (const int*)  d_in[13],  // internal_clock
        (float*)d_out);
}